// Round 3
// baseline (1410.157 us; speedup 1.0000x reference)
//
#include <hip/hip_runtime.h>
#include <hip/hip_bf16.h>

#define NPTS 200000
#define CIN 64
#define COUT 64
#define KVOL 27
#define NPAIRS 100000
#define NTOT (KVOL * NPAIRS)          // 2,700,000 pairs
#define RB 128                        // output rows per bucket
#define NB ((NPTS + RB - 1) / RB)     // 1563 buckets
#define NSEG (NB * KVOL)              // 42201 (bucket,k) segments
#define SCAN_BLOCKS ((NSEG + 255) / 256)  // 165
#define LIST_CAP (NTOT + NSEG * 15)   // worst-case pad-to-16
#define BN_EPS 1e-5f

typedef __attribute__((ext_vector_type(8))) short short8;
typedef __attribute__((ext_vector_type(4))) float f32x4;

__device__ inline ushort f2bf(float x) {
    union { __hip_bfloat16 h; ushort u; } cv;
    cv.h = __float2bfloat16(x);
    return cv.u;
}

// ---- Phase A ----------------------------------------------------------------

// Histogram pairs into (bucket,k) segments.
__global__ __launch_bounds__(256) void hist_kernel(
    const int* __restrict__ out_map, int* __restrict__ cnt)
{
    const int t = blockIdx.x * 256 + threadIdx.x;
    if (t >= NTOT) return;
    const int k = t / NPAIRS;
    const int o = out_map[t];
    atomicAdd(&cnt[(o >> 7) * KVOL + k], 1);
}

// Exclusive scan of pad16(cnt), 3-kernel pattern.
__global__ __launch_bounds__(256) void scan_block_kernel(
    const int* __restrict__ cnt, int* __restrict__ off, int* __restrict__ bsum)
{
    __shared__ int s[256];
    const int tid = threadIdx.x;
    const int idx = blockIdx.x * 256 + tid;
    const int v = (idx < NSEG) ? ((cnt[idx] + 15) & ~15) : 0;
    s[tid] = v;
    __syncthreads();
    for (int d = 1; d < 256; d <<= 1) {
        const int t = (tid >= d) ? s[tid - d] : 0;
        __syncthreads();
        s[tid] += t;
        __syncthreads();
    }
    if (idx < NSEG) off[idx] = s[tid] - v;
    if (tid == 255) bsum[blockIdx.x] = s[255];
}

__global__ __launch_bounds__(256) void scan_bsum_kernel(int* __restrict__ bsum)
{
    __shared__ int s[256];
    const int tid = threadIdx.x;
    const int v = (tid < SCAN_BLOCKS) ? bsum[tid] : 0;
    s[tid] = v;
    __syncthreads();
    for (int d = 1; d < 256; d <<= 1) {
        const int t = (tid >= d) ? s[tid - d] : 0;
        __syncthreads();
        s[tid] += t;
        __syncthreads();
    }
    if (tid < SCAN_BLOCKS) bsum[tid] = s[tid] - v;  // exclusive
}

__global__ __launch_bounds__(256) void add_offsets_kernel(
    int* __restrict__ off, const int* __restrict__ bsum)
{
    const int idx = blockIdx.x * 256 + threadIdx.x;
    if (idx < NSEG) off[idx] += bsum[blockIdx.x];
}

// Scatter pair records into padded segment lists.
// rec = in_row (18b) | local_out_row (7b) << 18 ; sentinel = -1 (from memset 0xFF).
__global__ __launch_bounds__(256) void fill_kernel(
    const int* __restrict__ in_map, const int* __restrict__ out_map,
    const int* __restrict__ off, int* __restrict__ cur, int* __restrict__ list)
{
    const int t = blockIdx.x * 256 + threadIdx.x;
    if (t >= NTOT) return;
    const int k = t / NPAIRS;
    const int o = out_map[t];
    const int seg = (o >> 7) * KVOL + k;
    const int slot = atomicAdd(&cur[seg], 1);
    list[off[seg] + slot] = in_map[t] | ((o & 127) << 18);
}

// Repack weights fp32 -> bf16 in lane-fragment order:
// wpack[((k*8 + h*4 + nt)*64 + lane)*8 + e] = W[k][h*32 + (lane>>4)*8 + e][nt*16 + (lane&15)]
__global__ __launch_bounds__(256) void repack_w_kernel(
    const float* __restrict__ wk, ushort* __restrict__ wpack)
{
    const int idx = blockIdx.x * 256 + threadIdx.x;
    if (idx >= KVOL * 8 * 64 * 8) return;
    const int e    = idx & 7;
    const int lane = (idx >> 3) & 63;
    const int f    = (idx >> 9) & 7;   // h*4 + nt
    const int k    = idx >> 12;
    const int h = f >> 2, nt = f & 3;
    const int q = lane >> 4, m = lane & 15;
    const int kin = h * 32 + q * 8 + e;
    wpack[idx] = f2bf(wk[k * (CIN * COUT) + kin * COUT + nt * 16 + m]);
}

// ---- Phase B: bucketed conv + LDS accumulate + fused BN/ReLU ---------------
__global__ __launch_bounds__(256) void conv_bucket_kernel(
    const float* __restrict__ feats,    // fp32 [NPTS][CIN]
    const ushort* __restrict__ wpack,   // bf16 fragments
    const int* __restrict__ off,        // [NSEG] padded exclusive offsets
    const int* __restrict__ cnt,        // [NSEG] raw counts
    const int* __restrict__ list,       // padded records
    const float* __restrict__ gamma, const float* __restrict__ beta,
    const float* __restrict__ rmean, const float* __restrict__ rvar,
    float* __restrict__ out)            // fp32 [NPTS][COUT]
{
    __shared__ float sacc[RB * COUT];   // 32 KB, XOR-bit4 swizzled by row parity

    const int b    = blockIdx.x;
    const int tid  = threadIdx.x;
    const int lane = tid & 63;
    const int wave = tid >> 6;
    const int m    = lane & 15;
    const int q    = lane >> 4;

    // Zero the LDS accumulator (swizzle irrelevant for zeroing).
    {
        f32x4* z = (f32x4*)sacc;
        #pragma unroll
        for (int i = 0; i < (RB * COUT / 4) / 256; ++i)
            z[tid + i * 256] = (f32x4){0.f, 0.f, 0.f, 0.f};
    }
    __syncthreads();

    #pragma unroll 1
    for (int k = 0; k < KVOL; ++k) {
        const int seg = b * KVOL + k;
        const int s0  = off[seg];
        const int ng  = (cnt[seg] + 15) >> 4;
        if (ng == 0) continue;

        // B fragments for this k: 8 x 16B vector loads.
        short8 bfrag[2][4];
        #pragma unroll
        for (int f = 0; f < 8; ++f)
            bfrag[f >> 2][f & 3] =
                *(const short8*)(wpack + ((size_t)(k * 8 + f) * 64 + lane) * 8);

        #pragma unroll 1
        for (int g = wave; g < ng; g += 4) {
            const int base = s0 + g * 16;
            const int rec  = list[base + m];   // lane m holds slot base+m
            const int row  = (rec >= 0) ? (rec & 0x3FFFF) : 0;

            // Gather A (fp32 -> bf16).
            const float* fr = feats + (size_t)row * CIN + q * 8;
            const f32x4 f00 = *(const f32x4*)(fr);
            const f32x4 f01 = *(const f32x4*)(fr + 4);
            const f32x4 f10 = *(const f32x4*)(fr + 32);
            const f32x4 f11 = *(const f32x4*)(fr + 36);
            short8 a0, a1;
            #pragma unroll
            for (int e = 0; e < 4; ++e) {
                a0[e]     = (short)f2bf(f00[e]);
                a0[e + 4] = (short)f2bf(f01[e]);
                a1[e]     = (short)f2bf(f10[e]);
                a1[e + 4] = (short)f2bf(f11[e]);
            }

            f32x4 acc[4];
            #pragma unroll
            for (int nt = 0; nt < 4; ++nt) acc[nt] = (f32x4){0.f, 0.f, 0.f, 0.f};
            #pragma unroll
            for (int nt = 0; nt < 4; ++nt) {
                acc[nt] = __builtin_amdgcn_mfma_f32_16x16x32_bf16(a0, bfrag[0][nt], acc[nt], 0, 0, 0);
                acc[nt] = __builtin_amdgcn_mfma_f32_16x16x32_bf16(a1, bfrag[1][nt], acc[nt], 0, 0, 0);
            }

            // Scatter D rows into LDS. D row r of quad q == slot base + q*4 + r,
            // whose record lives in lane q*4+r (0..15).
            #pragma unroll
            for (int r = 0; r < 4; ++r) {
                const int rec_r = __shfl(rec, q * 4 + r);
                if (rec_r >= 0) {
                    const int loc = rec_r >> 18;
                    const int sw  = (loc & 1) << 4;
                    #pragma unroll
                    for (int nt = 0; nt < 4; ++nt) {
                        const int c = nt * 16 + m;
                        atomicAdd(&sacc[loc * COUT + (c ^ sw)], acc[nt][r]);
                    }
                }
            }
        }
    }
    __syncthreads();

    // Fused BN + ReLU epilogue: thread t -> row loc = t>>1, cols [ (t&1)*32, +32 ).
    const int loc = tid >> 1;
    const int c0  = (tid & 1) * 32;
    const int gr  = b * RB + loc;
    if (gr < NPTS) {
        const int sw = (loc & 1) << 4;
        #pragma unroll
        for (int cc = 0; cc < 32; cc += 4) {
            const int c = c0 + cc;
            const f32x4 v = *(const f32x4*)(&sacc[loc * COUT + (c ^ sw)]);
            f32x4 o;
            #pragma unroll
            for (int e = 0; e < 4; ++e) {
                const float sc = gamma[c + e] * rsqrtf(rvar[c + e] + BN_EPS);
                const float bi = beta[c + e] - rmean[c + e] * sc;
                o[e] = fmaxf(v[e] * sc + bi, 0.f);
            }
            *(f32x4*)(out + (size_t)gr * COUT + c) = o;
        }
    }
}

// ---- launch -----------------------------------------------------------------
extern "C" void kernel_launch(void* const* d_in, const int* in_sizes, int n_in,
                              void* d_out, int out_size, void* d_ws, size_t ws_size,
                              hipStream_t stream) {
    const float* feats = (const float*)d_in[0];
    const float* wk    = (const float*)d_in[1];
    const float* gamma = (const float*)d_in[2];
    const float* beta  = (const float*)d_in[3];
    const float* rmean = (const float*)d_in[4];
    const float* rvar  = (const float*)d_in[5];
    const int* imap    = (const int*)d_in[6];
    const int* omap    = (const int*)d_in[7];
    float* out         = (float*)d_out;

    // Workspace carve-up (1 KB aligned), total ~14.4 MB.
    char* ws = (char*)d_ws;
    auto align1k = [](size_t x) { return (x + 1023) & ~(size_t)1023; };
    size_t p = 0;
    int* cnt      = (int*)(ws + p); p += align1k(NSEG * 4);
    int* cur      = (int*)(ws + p); p += align1k(NSEG * 4);
    int* off      = (int*)(ws + p); p += align1k(NSEG * 4);
    int* bsum     = (int*)(ws + p); p += align1k(256 * 4);
    ushort* wpack = (ushort*)(ws + p); p += align1k((size_t)KVOL * 8 * 64 * 8 * 2);
    int* list     = (int*)(ws + p); p += align1k((size_t)LIST_CAP * 4);

    hipMemsetAsync(cnt, 0, NSEG * 4, stream);
    hipMemsetAsync(cur, 0, NSEG * 4, stream);
    hipMemsetAsync(list, 0xFF, (size_t)LIST_CAP * 4, stream);

    const int pb = (NTOT + 255) / 256;
    hist_kernel<<<pb, 256, 0, stream>>>(omap, cnt);
    scan_block_kernel<<<SCAN_BLOCKS, 256, 0, stream>>>(cnt, off, bsum);
    scan_bsum_kernel<<<1, 256, 0, stream>>>(bsum);
    add_offsets_kernel<<<SCAN_BLOCKS, 256, 0, stream>>>(off, bsum);
    fill_kernel<<<pb, 256, 0, stream>>>(imap, omap, off, cur, list);
    repack_w_kernel<<<(KVOL * 8 * 64 * 8 + 255) / 256, 256, 0, stream>>>(wk, wpack);

    conv_bucket_kernel<<<NB, 256, 0, stream>>>(
        feats, wpack, off, cnt, list, gamma, beta, rmean, rvar, out);
}

// Round 4
// 675.110 us; speedup vs baseline: 2.0888x; 2.0888x over previous
//
#include <hip/hip_runtime.h>
#include <hip/hip_bf16.h>

#define NPTS 200000
#define CIN 64
#define COUT 64
#define KVOL 27
#define NPAIRS 100000
#define GROUPS_PER_K (NPAIRS / 16)                                               // 6250
#define GROUPS_PER_BLOCK 64
#define CHUNKS_PER_K ((GROUPS_PER_K + GROUPS_PER_BLOCK - 1) / GROUPS_PER_BLOCK)  // 98
#define BN_EPS 1e-5f

typedef __attribute__((ext_vector_type(8))) short short8;   // 8 bf16 bits (4 VGPRs)
typedef __attribute__((ext_vector_type(4))) float f32x4;

__device__ inline ushort f2bf(float x) {
    union { __hip_bfloat16 h; ushort u; } cv;
    cv.h = __float2bfloat16(x);   // RNE
    return cv.u;
}

// Per 16-pair group, one wave computes contrib[16 pairs][64 cout] via 8 MFMAs
// (M16 x N64 x K64) and scatters fp32 into accum with NATIVE fp atomics
// (unsafeAtomicAdd -> global_atomic_add_f32; plain atomicAdd is a CAS loop
// without -munsafe-fp-atomics, which was the R2/R3 bottleneck).
//  A[m=lane&15][k=q*8+e]   (verified A-operand layout, q=lane>>4)
//  B[k=q*8+e][j=lane&15]   (mirror layout)
//  D: pair=q*4+reg, cout=ntile*16+(lane&15)   (verified C/D layout)
__global__ __launch_bounds__(256) void conv_scatter_kernel(
    const float* __restrict__ feats,      // fp32 [NPTS][CIN]
    const float* __restrict__ wk,         // fp32 [KVOL][CIN][COUT]
    const int* __restrict__ in_map,       // [KVOL][NPAIRS]
    const int* __restrict__ out_map,      // [KVOL][NPAIRS]
    float* __restrict__ accum)            // [NPTS][COUT] fp32
{
    const int koff  = blockIdx.x / CHUNKS_PER_K;
    const int chunk = blockIdx.x % CHUNKS_PER_K;
    const int lane  = threadIdx.x & 63;
    const int wave  = threadIdx.x >> 6;
    const int m     = lane & 15;
    const int q     = lane >> 4;

    // Load W[koff] fragments (fp32 -> bf16) once per block; amortized over 64 groups.
    short8 bfrag[2][4];
    const float* wbase = wk + koff * (CIN * COUT);
    #pragma unroll
    for (int h = 0; h < 2; ++h) {
        #pragma unroll
        for (int nt = 0; nt < 4; ++nt) {
            #pragma unroll
            for (int e = 0; e < 8; ++e) {
                const int kin = h * 32 + q * 8 + e;
                bfrag[h][nt][e] = (short)f2bf(wbase[kin * COUT + nt * 16 + m]);
            }
        }
    }

    const int* imap = in_map + koff * NPAIRS;
    const int* omap = out_map + koff * NPAIRS;

    #pragma unroll 1
    for (int it = 0; it < GROUPS_PER_BLOCK / 4; ++it) {
        const int g = chunk * GROUPS_PER_BLOCK + it * 4 + wave;
        if (g >= GROUPS_PER_K) break;
        const int base = g * 16;

        // Gather A: lane m owns row in_map[base+m]; cols q*8..q*8+7 (a0) and +32 (a1).
        const int row = imap[base + m];
        const float* fr = feats + (size_t)row * CIN + q * 8;
        const f32x4 f00 = *(const f32x4*)(fr);
        const f32x4 f01 = *(const f32x4*)(fr + 4);
        const f32x4 f10 = *(const f32x4*)(fr + 32);
        const f32x4 f11 = *(const f32x4*)(fr + 36);

        short8 a0, a1;
        #pragma unroll
        for (int e = 0; e < 4; ++e) {
            a0[e]     = (short)f2bf(f00[e]);
            a0[e + 4] = (short)f2bf(f01[e]);
            a1[e]     = (short)f2bf(f10[e]);
            a1[e + 4] = (short)f2bf(f11[e]);
        }

        f32x4 acc[4];
        #pragma unroll
        for (int nt = 0; nt < 4; ++nt) acc[nt] = (f32x4){0.f, 0.f, 0.f, 0.f};
        #pragma unroll
        for (int nt = 0; nt < 4; ++nt) {
            acc[nt] = __builtin_amdgcn_mfma_f32_16x16x32_bf16(a0, bfrag[0][nt], acc[nt], 0, 0, 0);
            acc[nt] = __builtin_amdgcn_mfma_f32_16x16x32_bf16(a1, bfrag[1][nt], acc[nt], 0, 0, 0);
        }

        int orow[4];
        #pragma unroll
        for (int r = 0; r < 4; ++r) orow[r] = omap[base + q * 4 + r];

        #pragma unroll
        for (int nt = 0; nt < 4; ++nt) {
            #pragma unroll
            for (int r = 0; r < 4; ++r) {
                unsafeAtomicAdd(accum + (size_t)orow[r] * COUT + nt * 16 + m, acc[nt][r]);
            }
        }
    }
}

// BN (inference-folded) + ReLU; fp32 accum -> fp32 out.
__global__ __launch_bounds__(256) void bn_relu_kernel(
    const float* __restrict__ accum,
    const float* __restrict__ gamma,
    const float* __restrict__ beta,
    const float* __restrict__ rmean,
    const float* __restrict__ rvar,
    float* __restrict__ out)
{
    __shared__ float s_scale[COUT];
    __shared__ float s_bias[COUT];
    if (threadIdx.x < COUT) {
        const int c = threadIdx.x;
        const float sc = gamma[c] * rsqrtf(rvar[c] + BN_EPS);
        s_scale[c] = sc;
        s_bias[c]  = beta[c] - rmean[c] * sc;
    }
    __syncthreads();

    const int idx = (blockIdx.x * 256 + threadIdx.x) * 4;
    if (idx < NPTS * COUT) {
        const f32x4 v = *(const f32x4*)(accum + idx);
        const int c0 = idx & (COUT - 1);   // 4 | COUT, so c0..c0+3 stay in-row
        f32x4 o;
        #pragma unroll
        for (int e = 0; e < 4; ++e) {
            o[e] = fmaxf(v[e] * s_scale[c0 + e] + s_bias[c0 + e], 0.f);
        }
        *(f32x4*)(out + idx) = o;
    }
}

extern "C" void kernel_launch(void* const* d_in, const int* in_sizes, int n_in,
                              void* d_out, int out_size, void* d_ws, size_t ws_size,
                              hipStream_t stream) {
    const float* feats = (const float*)d_in[0];
    const float* wk    = (const float*)d_in[1];
    const float* gamma = (const float*)d_in[2];
    const float* beta  = (const float*)d_in[3];
    const float* rmean = (const float*)d_in[4];
    const float* rvar  = (const float*)d_in[5];
    const int* imap    = (const int*)d_in[6];
    const int* omap    = (const int*)d_in[7];
    float* out         = (float*)d_out;
    float* accum       = (float*)d_ws;   // 200000*64*4 = 51.2 MB scratch

    hipMemsetAsync(accum, 0, (size_t)NPTS * COUT * sizeof(float), stream);

    conv_scatter_kernel<<<KVOL * CHUNKS_PER_K, 256, 0, stream>>>(feats, wk, imap, omap, accum);

    bn_relu_kernel<<<(NPTS * COUT / 4 + 255) / 256, 256, 0, stream>>>(
        accum, gamma, beta, rmean, rvar, out);
}